// Round 7
// baseline (317.269 us; speedup 1.0000x reference)
//
#include <hip/hip_runtime.h>
#include <hip/hip_bf16.h>

// DotProductAttention B=2,H=16,S=2048,D=64 fp32 in/out, int32 mask (B,1,S,S).
// R6: occupancy attack. R2 was grid-capped at 16 waves/CU (1024 blocks x 4
//     waves; 13 resident observed) and latency-bound (MFMA 8.5%, VALU 30%,
//     HBM 13%). Split each chunk's KEYS across wave pairs: block = 2 q-tiles
//     x 2 key-halves (BQ=32), grid 2048 blocks, 8192 waves, LDS 27.6KB ->
//     5-6 blocks/CU = 20-24 waves/CU. Per-wave chunk chain halves (4 QK
//     MFMA + 8 exp + 4 PV MFMA). In-block merge of the two (m,l,O) partials
//     at the end (flash combine, overlays dead sK as scratch).
//     R3/R4/R5 lesson: no reg-prefetch, no dbuf - R2's simple 2-barrier
//     staging + max resident waves wins.
//  - S^T = K*Q^T: softmax stats one-query-per-lane-column (2 shuffles).
//  - base-2 softmax (0.125*log2e folded into Q, mask -> -1e9*log2e).
//  - P: C-layout -> A-layout via per-wave LDS round trip (32-key rows).
//  - V transposed in LDS [d][key]; K/V rows 144B for aligned b128.
//  - SQ_LDS_BANK_CONFLICT 1.15e7 = b128 floor (R2..R5 constant), ignore.

#define B_ 2
#define H_ 16
#define S_ 2048
#define D_ 64
#define BQ 32     // queries per block: 2 q-tiles of 16
#define BK 64     // keys staged per chunk (shared by both key-half waves)
#define PADW 72   // K/V LDS row stride in bf16 (144 B)
#define PADP 40   // sP row stride in bf16 (80 B, 16B-aligned)

typedef __attribute__((ext_vector_type(4))) float f32x4;
typedef __attribute__((ext_vector_type(8))) short bf16x8;
typedef __attribute__((ext_vector_type(4))) short bf16x4;

#define QSCALE 0.1803368801111137f       // 0.125 * log2(e)
#define MASKNEG (-1.4426950408889634e9f) // -1e9 * log2(e)

static __device__ __forceinline__ short f2bf(float f) {
  __hip_bfloat16 h = __float2bfloat16(f);
  short s; __builtin_memcpy(&s, &h, sizeof(s)); return s;
}
static __device__ __forceinline__ float fexp2(float x) {
  return __builtin_amdgcn_exp2f(x);
}

__global__ __launch_bounds__(256, 4)
void attn_mfma(const float* __restrict__ qg, const float* __restrict__ kg,
               const float* __restrict__ vg, const int* __restrict__ maskg,
               float* __restrict__ outg) {
  __shared__ short sK[BK][PADW];      // [key][d]   bf16 (full 64-key chunk)
  __shared__ short sVT[D_][PADW];     // [d][key]   bf16 (transposed V)
  __shared__ short sP[4][16][PADP];   // per-wave P [q][key-local 32]

  const int tid  = threadIdx.x;
  const int lane = tid & 63;
  const int wv   = tid >> 6;
  const int l15  = lane & 15;
  const int quad = lane >> 4;
  const int qt   = wv & 1;            // which 16-query tile
  const int kh   = wv >> 1;           // which 32-key half of each chunk

  const int bh = blockIdx.y;          // 0..31
  const int b  = bh >> 4;
  const int q0 = blockIdx.x * BQ;
  const int qi = q0 + qt * 16 + l15;  // this lane's stats-query row

  // ---- Q fragments (B-operand: lane holds Q[q=l15][d=ks*32+quad*8+j]) ----
  bf16x8 qf[2];
  {
    const float* qrow = qg + ((size_t)bh * S_ + qi) * D_;
    #pragma unroll
    for (int ks = 0; ks < 2; ++ks) {
      const float4 u0 = *(const float4*)(qrow + ks*32 + quad*8);
      const float4 u1 = *(const float4*)(qrow + ks*32 + quad*8 + 4);
      bf16x8 f;
      f[0]=f2bf(u0.x*QSCALE); f[1]=f2bf(u0.y*QSCALE);
      f[2]=f2bf(u0.z*QSCALE); f[3]=f2bf(u0.w*QSCALE);
      f[4]=f2bf(u1.x*QSCALE); f[5]=f2bf(u1.y*QSCALE);
      f[6]=f2bf(u1.z*QSCALE); f[7]=f2bf(u1.w*QSCALE);
      qf[ks] = f;
    }
  }

  f32x4 O[4];
  #pragma unroll
  for (int dt = 0; dt < 4; ++dt) O[dt] = (f32x4){0.f, 0.f, 0.f, 0.f};
  float m = -3.0e38f, l = 0.f;        // partial stats over THIS key-half

  const float* kbase = kg + (size_t)bh * S_ * D_;
  const float* vbase = vg + (size_t)bh * S_ * D_;
  const int*   mrow  = maskg + ((size_t)b * S_ + qi) * S_;

  for (int t0 = 0; t0 < S_; t0 += BK) {
    __syncthreads();
    // ---- stage K tile [key][d], fp32->bf16 (R2's staging, unchanged) ----
    #pragma unroll
    for (int i = 0; i < 4; ++i) {
      const int id = tid + 256*i;
      const int key = id >> 4, d4 = (id & 15) * 4;
      const float4 u = *(const float4*)(kbase + (size_t)(t0 + key)*D_ + d4);
      bf16x4 w; w[0]=f2bf(u.x); w[1]=f2bf(u.y); w[2]=f2bf(u.z); w[3]=f2bf(u.w);
      *(bf16x4*)&sK[key][d4] = w;
    }
    // ---- stage V^T tile [d][key] ----
    #pragma unroll
    for (int i = 0; i < 2; ++i) {
      const int id = tid + 256*i;
      const int kp = id & 31, d4 = (id >> 5) * 4;
      const float4 a = *(const float4*)(vbase + (size_t)(t0 + 2*kp    )*D_ + d4);
      const float4 c = *(const float4*)(vbase + (size_t)(t0 + 2*kp + 1)*D_ + d4);
      const float av[4] = {a.x, a.y, a.z, a.w};
      const float cv[4] = {c.x, c.y, c.z, c.w};
      #pragma unroll
      for (int j = 0; j < 4; ++j) {
        const unsigned pk = (unsigned)(unsigned short)f2bf(av[j])
                          | ((unsigned)(unsigned short)f2bf(cv[j]) << 16);
        *(unsigned*)&sVT[d4 + j][2*kp] = pk;
      }
    }
    __syncthreads();

    // ---- mask: this lane's q row, this wave's 32 keys ----
    int4 mk[2];
    #pragma unroll
    for (int mt = 0; mt < 2; ++mt)
      mk[mt] = *(const int4*)(mrow + t0 + kh*32 + mt*16 + quad*4);

    // ---- S^T = K*Q^T over this key-half: 2 tiles x 2 K-steps = 4 MFMA ----
    f32x4 st[2];
    #pragma unroll
    for (int mt = 0; mt < 2; ++mt) {
      f32x4 acc = (f32x4){0.f, 0.f, 0.f, 0.f};
      #pragma unroll
      for (int ks = 0; ks < 2; ++ks) {
        const bf16x8 kf =
            *(const bf16x8*)&sK[kh*32 + mt*16 + l15][ks*32 + quad*8];
        acc = __builtin_amdgcn_mfma_f32_16x16x32_bf16(kf, qf[ks], acc, 0, 0, 0);
      }
      st[mt] = acc;
    }

    // ---- mask + half-chunk max ----
    float cmax = -3.0e38f;
    #pragma unroll
    for (int mt = 0; mt < 2; ++mt) {
      f32x4 s = st[mt];
      s.x = mk[mt].x ? s.x : MASKNEG;
      s.y = mk[mt].y ? s.y : MASKNEG;
      s.z = mk[mt].z ? s.z : MASKNEG;
      s.w = mk[mt].w ? s.w : MASKNEG;
      st[mt] = s;
      cmax = fmaxf(cmax, fmaxf(fmaxf(s.x, s.y), fmaxf(s.z, s.w)));
    }
    cmax = fmaxf(cmax, __shfl_xor(cmax, 16));
    cmax = fmaxf(cmax, __shfl_xor(cmax, 32));
    const float mnew  = fmaxf(m, cmax);
    const float alpha = fexp2(m - mnew);   // ==0 on first chunk (m=-3e38)
    m = mnew;

    // ---- P = exp2(S - m), accumulate l, write P to per-wave LDS ----
    float lsum = 0.f;
    #pragma unroll
    for (int mt = 0; mt < 2; ++mt) {
      const float p0 = fexp2(st[mt].x - mnew);
      const float p1 = fexp2(st[mt].y - mnew);
      const float p2 = fexp2(st[mt].z - mnew);
      const float p3 = fexp2(st[mt].w - mnew);
      lsum += (p0 + p1) + (p2 + p3);
      bf16x4 pw; pw[0]=f2bf(p0); pw[1]=f2bf(p1); pw[2]=f2bf(p2); pw[3]=f2bf(p3);
      *(bf16x4*)&sP[wv][l15][mt*16 + quad*4] = pw;
    }
    lsum += __shfl_xor(lsum, 16);   // quad-replicas hold 8/32 keys each
    lsum += __shfl_xor(lsum, 32);
    l = l * alpha + lsum;

    // ---- rescale O: alpha per O-row from stats lanes ----
    const float ar0 = __shfl(alpha, quad*4 + 0);
    const float ar1 = __shfl(alpha, quad*4 + 1);
    const float ar2 = __shfl(alpha, quad*4 + 2);
    const float ar3 = __shfl(alpha, quad*4 + 3);
    #pragma unroll
    for (int dt = 0; dt < 4; ++dt) {
      O[dt].x *= ar0; O[dt].y *= ar1; O[dt].z *= ar2; O[dt].w *= ar3;
    }

    // wave-internal: drain ds writes (sP visible across lanes of this wave)
    asm volatile("s_waitcnt lgkmcnt(0)" ::: "memory");

    // ---- O += P*V over this key-half: 1 A-frag, 4 MFMA ----
    const bf16x8 pf = *(const bf16x8*)&sP[wv][l15][quad*8];
    #pragma unroll
    for (int dt = 0; dt < 4; ++dt) {
      const bf16x8 vf = *(const bf16x8*)&sVT[dt*16 + l15][kh*32 + quad*8];
      O[dt] = __builtin_amdgcn_mfma_f32_16x16x32_bf16(pf, vf, O[dt], 0, 0, 0);
    }
  }

  // ==== merge the two key-half partials (flash combine), then store ====
  __syncthreads();                      // last chunk's LDS reads done
  // overlay scratch on dead sK: per qt, 16x68 O-floats + 16 m + 16 l
  float* mb = (float*)&sK[0][0] + qt * 1120;

  if (kh == 1) {
    #pragma unroll
    for (int dt = 0; dt < 4; ++dt) {
      mb[(quad*4 + 0)*68 + dt*16 + l15] = O[dt].x;
      mb[(quad*4 + 1)*68 + dt*16 + l15] = O[dt].y;
      mb[(quad*4 + 2)*68 + dt*16 + l15] = O[dt].z;
      mb[(quad*4 + 3)*68 + dt*16 + l15] = O[dt].w;
    }
    if (quad == 0) { mb[1088 + l15] = m; mb[1104 + l15] = l; }
  }
  __syncthreads();

  if (kh == 0) {
    const float m2 = mb[1088 + l15];
    const float l2 = mb[1104 + l15];
    const float M  = fmaxf(m, m2);
    const float a1 = fexp2(m  - M);
    const float a2 = fexp2(m2 - M);
    const float Li = 1.0f / (l * a1 + l2 * a2);
    // per-O-row broadcasts from stats lanes
    float a1r[4], a2r[4], Lir[4];
    #pragma unroll
    for (int r = 0; r < 4; ++r) {
      a1r[r] = __shfl(a1, quad*4 + r);
      a2r[r] = __shfl(a2, quad*4 + r);
      Lir[r] = __shfl(Li, quad*4 + r);
    }
    float* ob = outg + ((size_t)bh * S_ + q0 + qt*16) * D_;
    #pragma unroll
    for (int dt = 0; dt < 4; ++dt) {
      const float o20 = mb[(quad*4 + 0)*68 + dt*16 + l15];
      const float o21 = mb[(quad*4 + 1)*68 + dt*16 + l15];
      const float o22 = mb[(quad*4 + 2)*68 + dt*16 + l15];
      const float o23 = mb[(quad*4 + 3)*68 + dt*16 + l15];
      ob[(quad*4 + 0)*D_ + dt*16 + l15] = (O[dt].x*a1r[0] + o20*a2r[0])*Lir[0];
      ob[(quad*4 + 1)*D_ + dt*16 + l15] = (O[dt].y*a1r[1] + o21*a2r[1])*Lir[1];
      ob[(quad*4 + 2)*D_ + dt*16 + l15] = (O[dt].z*a1r[2] + o22*a2r[2])*Lir[2];
      ob[(quad*4 + 3)*D_ + dt*16 + l15] = (O[dt].w*a1r[3] + o23*a2r[3])*Lir[3];
    }
  }
}

extern "C" void kernel_launch(void* const* d_in, const int* in_sizes, int n_in,
                              void* d_out, int out_size, void* d_ws, size_t ws_size,
                              hipStream_t stream) {
  const float* q    = (const float*)d_in[0];
  const float* k    = (const float*)d_in[1];
  const float* v    = (const float*)d_in[2];
  const int*   mask = (const int*)d_in[3];
  float* out = (float*)d_out;

  dim3 grid(S_ / BQ, B_ * H_);   // (64, 32) = 2048 blocks, 4 waves each
  attn_mfma<<<grid, 256, 0, stream>>>(q, k, v, mask, out);
}

// Round 8
// 243.623 us; speedup vs baseline: 1.3023x; 1.3023x over previous
//
#include <hip/hip_runtime.h>
#include <hip/hip_bf16.h>

// DotProductAttention B=2,H=16,S=2048,D=64 fp32 in/out, int32 mask (B,1,S,S).
// R7: 32x32x16 MFMA redesign. Same grid (1024 blocks) + byte-identical
//     staging as R2 (best known). Per block: 2 q-tiles x 2 key-halves,
//     wave = 32q x 32k. Wins vs R2's 16x16x32:
//     - fragment LDS traffic halved (one b128 A-frag per 16k MACs)
//     - S^T=K*Q^T AND O^T=V^T*P^T keep q in the lane index for BOTH
//       C-layouts -> softmax stats/alpha/1/l are per-lane, no sA broadcast
//     - P's C->B transform = in-register half-wave exchange (4 shfl_xor(32)
//       + cndmasks), sP LDS buffer + full lgkmcnt drain eliminated
//     - MFMA instruction count halved at same FLOPs
//     Final 2-way merge (flash combine) per q-tile via sO scratch, once per
//     block; coalesced float4 epilogue store through LDS.
// Layouts (guide-verified): 32x32x16 A[m=lane&31][k=(lane>>5)*8+j],
//     B[k=(lane>>5)*8+j][n=lane&31], C col=lane&31,
//     row=(reg&3)+8*(reg>>2)+4*(lane>>5).

#define B_ 2
#define H_ 16
#define S_ 2048
#define D_ 64
#define BQ 64
#define BK 64
#define PADW 72   // K/V LDS row stride in bf16 (144 B, 16B-aligned rows)
#define PADO 68   // sO row stride in floats (272 B, 16B-aligned rows)

typedef __attribute__((ext_vector_type(16))) float f32x16;
typedef __attribute__((ext_vector_type(8))) short bf16x8;
typedef __attribute__((ext_vector_type(4))) short bf16x4;

#define QSCALE 0.1803368801111137f       // 0.125 * log2(e)
#define MASKNEG (-1.4426950408889634e9f) // -1e9 * log2(e)

static __device__ __forceinline__ short f2bf(float f) {
  __hip_bfloat16 h = __float2bfloat16(f);
  short s; __builtin_memcpy(&s, &h, sizeof(s)); return s;
}
static __device__ __forceinline__ unsigned pack2(float a, float b) {
  return (unsigned)(unsigned short)f2bf(a)
       | ((unsigned)(unsigned short)f2bf(b) << 16);
}
static __device__ __forceinline__ float fexp2(float x) {
  return __builtin_amdgcn_exp2f(x);
}

__global__ __launch_bounds__(256, 4)
void attn_mfma(const float* __restrict__ qg, const float* __restrict__ kg,
               const float* __restrict__ vg, const int* __restrict__ maskg,
               float* __restrict__ outg) {
  __shared__ short sK[BK][PADW];      // [key][d]  bf16
  __shared__ short sVT[D_][PADW];     // [d][key]  bf16 (transposed V)
  __shared__ float sO[BQ][PADO];      // merge/store scratch (epilogue only)
  __shared__ float sM[BQ], sL[BQ];    // merge stats (epilogue only)

  const int tid  = threadIdx.x;
  const int lane = tid & 63;
  const int wv   = tid >> 6;
  const int q31  = lane & 31;
  const int h    = lane >> 5;         // half-wave index (k-split of frags)
  const int qt   = wv & 1;            // q-tile (32 queries)
  const int kh   = wv >> 1;           // key-half of each 64-key chunk

  const int bh = blockIdx.y;
  const int b  = bh >> 4;
  const int q0 = blockIdx.x * BQ;
  const int qi = q0 + qt * 32 + q31;  // this lane's query row

  // ---- Q frags (B-op): lane holds Q[qi][16i + 8h + j], j=0..7 ----
  bf16x8 qf[4];
  {
    const float* qrow = qg + ((size_t)bh * S_ + qi) * D_;
    #pragma unroll
    for (int i = 0; i < 4; ++i) {
      const float4 u0 = *(const float4*)(qrow + 16*i + 8*h);
      const float4 u1 = *(const float4*)(qrow + 16*i + 8*h + 4);
      bf16x8 f;
      f[0]=f2bf(u0.x*QSCALE); f[1]=f2bf(u0.y*QSCALE);
      f[2]=f2bf(u0.z*QSCALE); f[3]=f2bf(u0.w*QSCALE);
      f[4]=f2bf(u1.x*QSCALE); f[5]=f2bf(u1.y*QSCALE);
      f[6]=f2bf(u1.z*QSCALE); f[7]=f2bf(u1.w*QSCALE);
      qf[i] = f;
    }
  }

  f32x16 O[2];   // O^T[d = dt*32 + dloc(r,h)][q = q31]
  #pragma unroll
  for (int dt = 0; dt < 2; ++dt)
    #pragma unroll
    for (int r = 0; r < 16; ++r) O[dt][r] = 0.f;
  float m = -3.0e38f, l = 0.f;

  const float* kbase = kg + (size_t)bh * S_ * D_;
  const float* vbase = vg + (size_t)bh * S_ * D_;
  const int*   mrow  = maskg + ((size_t)b * S_ + qi) * S_;

  for (int t0 = 0; t0 < S_; t0 += BK) {
    __syncthreads();
    // ---- stage K tile [key][d], fp32->bf16 (R2 verbatim) ----
    #pragma unroll
    for (int i = 0; i < 4; ++i) {
      const int id = tid + 256*i;
      const int key = id >> 4, d4 = (id & 15) * 4;
      const float4 u = *(const float4*)(kbase + (size_t)(t0 + key)*D_ + d4);
      bf16x4 w; w[0]=f2bf(u.x); w[1]=f2bf(u.y); w[2]=f2bf(u.z); w[3]=f2bf(u.w);
      *(bf16x4*)&sK[key][d4] = w;
    }
    // ---- stage V^T tile [d][key] (R2 verbatim) ----
    #pragma unroll
    for (int i = 0; i < 2; ++i) {
      const int id = tid + 256*i;
      const int kp = id & 31, d4 = (id >> 5) * 4;
      const float4 a = *(const float4*)(vbase + (size_t)(t0 + 2*kp    )*D_ + d4);
      const float4 c = *(const float4*)(vbase + (size_t)(t0 + 2*kp + 1)*D_ + d4);
      const float av[4] = {a.x, a.y, a.z, a.w};
      const float cv[4] = {c.x, c.y, c.z, c.w};
      #pragma unroll
      for (int j = 0; j < 4; ++j) {
        const unsigned pk = (unsigned)(unsigned short)f2bf(av[j])
                          | ((unsigned)(unsigned short)f2bf(cv[j]) << 16);
        *(unsigned*)&sVT[d4 + j][2*kp] = pk;
      }
    }
    __syncthreads();

    // ---- S^T = K*Q^T : 4 MFMA over d; C[key=dloc(r,h)][q=q31] ----
    f32x16 acc;
    #pragma unroll
    for (int r = 0; r < 16; ++r) acc[r] = 0.f;
    #pragma unroll
    for (int i = 0; i < 4; ++i) {
      const bf16x8 kf = *(const bf16x8*)&sK[kh*32 + q31][16*i + 8*h];
      acc = __builtin_amdgcn_mfma_f32_32x32x16_bf16(kf, qf[i], acc, 0, 0, 0);
    }

    // ---- mask (this lane's q row; key = t0 + kh*32 + (r&3)+8*(r>>2)+4h) ----
    int4 mk[4];
    #pragma unroll
    for (int a = 0; a < 4; ++a)
      mk[a] = *(const int4*)(mrow + t0 + kh*32 + 8*a + 4*h);

    float cmax = -3.0e38f;
    #pragma unroll
    for (int a = 0; a < 4; ++a) {
      acc[4*a+0] = mk[a].x ? acc[4*a+0] : MASKNEG;
      acc[4*a+1] = mk[a].y ? acc[4*a+1] : MASKNEG;
      acc[4*a+2] = mk[a].z ? acc[4*a+2] : MASKNEG;
      acc[4*a+3] = mk[a].w ? acc[4*a+3] : MASKNEG;
      cmax = fmaxf(cmax, fmaxf(fmaxf(acc[4*a+0], acc[4*a+1]),
                               fmaxf(acc[4*a+2], acc[4*a+3])));
    }
    cmax = fmaxf(cmax, __shfl_xor(cmax, 32));    // other k-half, same q
    const float mnew  = fmaxf(m, cmax);
    const float alpha = fexp2(m - mnew);         // ==0 on first chunk
    m = mnew;

    // ---- P = exp2(S-m) in place, sum, pack to bf16 dwords ----
    float lsum = 0.f;
    #pragma unroll
    for (int r = 0; r < 16; ++r) {
      acc[r] = fexp2(acc[r] - mnew);
      lsum += acc[r];
    }
    unsigned dw[8];
    #pragma unroll
    for (int i = 0; i < 8; ++i) dw[i] = pack2(acc[2*i], acc[2*i+1]);
    lsum += __shfl_xor(lsum, 32);                // both k-halves of this q
    l = l * alpha + lsum;

    // ---- rescale O (q is the lane index: per-lane, no broadcast) ----
    #pragma unroll
    for (int dt = 0; dt < 2; ++dt)
      #pragma unroll
      for (int r = 0; r < 16; ++r) O[dt][r] *= alpha;

    // ---- P: C-layout -> B-layout via half-wave exchange ----
    // frag(ks) elem e: key = kh*32 + ks*16 + 8h + e; e<4 lives in h=0 lanes,
    // e>=4 in h=1 lanes, at dwords {4ks+2h', 4ks+2h'+1} of source half h'.
    const bool h1 = (h != 0);
    const unsigned s0 = h1 ? dw[0] : dw[2];
    const unsigned s1 = h1 ? dw[1] : dw[3];
    const unsigned s2 = h1 ? dw[4] : dw[6];
    const unsigned s3 = h1 ? dw[5] : dw[7];
    const unsigned r0 = (unsigned)__shfl_xor((int)s0, 32);
    const unsigned r1 = (unsigned)__shfl_xor((int)s1, 32);
    const unsigned r2 = (unsigned)__shfl_xor((int)s2, 32);
    const unsigned r3 = (unsigned)__shfl_xor((int)s3, 32);

    union { unsigned u[4]; bf16x8 v; } pf0, pf1;
    pf0.u[0] = h1 ? r0 : dw[0];  pf0.u[1] = h1 ? r1 : dw[1];
    pf0.u[2] = h1 ? dw[2] : r0;  pf0.u[3] = h1 ? dw[3] : r1;
    pf1.u[0] = h1 ? r2 : dw[4];  pf1.u[1] = h1 ? r3 : dw[5];
    pf1.u[2] = h1 ? dw[6] : r2;  pf1.u[3] = h1 ? dw[7] : r3;

    // ---- O^T += V^T * P^T : 2 d-tiles x 2 k-steps ----
    #pragma unroll
    for (int dt = 0; dt < 2; ++dt) {
      const bf16x8 vf0 = *(const bf16x8*)&sVT[dt*32 + q31][kh*32 + 8*h];
      const bf16x8 vf1 = *(const bf16x8*)&sVT[dt*32 + q31][kh*32 + 16 + 8*h];
      O[dt] = __builtin_amdgcn_mfma_f32_32x32x16_bf16(vf0, pf0.v, O[dt], 0, 0, 0);
      O[dt] = __builtin_amdgcn_mfma_f32_32x32x16_bf16(vf1, pf1.v, O[dt], 0, 0, 0);
    }
  }

  // ==== 2-way key-half merge (flash combine) + coalesced store ====
  const int qrow_l = qt*32 + q31;      // row in sO
  if (kh == 1) {
    #pragma unroll
    for (int dt = 0; dt < 2; ++dt)
      #pragma unroll
      for (int r = 0; r < 16; ++r) {
        const int dloc = (r & 3) + 8*(r >> 2) + 4*h;
        sO[qrow_l][dt*32 + dloc] = O[dt][r];
      }
    if (h == 0) { sM[qrow_l] = m; sL[qrow_l] = l; }
  }
  __syncthreads();
  if (kh == 0) {
    const float m2 = sM[qrow_l], l2 = sL[qrow_l];
    const float M  = fmaxf(m, m2);
    const float a1 = fexp2(m - M);
    const float a2 = fexp2(m2 - M);
    const float Li = 1.0f / (l * a1 + l2 * a2);
    #pragma unroll
    for (int dt = 0; dt < 2; ++dt)
      #pragma unroll
      for (int r = 0; r < 16; ++r) {
        const int dloc = (r & 3) + 8*(r >> 2) + 4*h;
        const float o2 = sO[qrow_l][dt*32 + dloc];
        sO[qrow_l][dt*32 + dloc] = (O[dt][r]*a1 + o2*a2) * Li;
      }
  }
  __syncthreads();
  // cooperative coalesced store: 64 rows x 16 float4
  #pragma unroll
  for (int it = 0; it < 4; ++it) {
    const int j = tid + 256*it;
    const int row = j >> 4, c4 = (j & 15) * 4;
    const float4 val = *(const float4*)&sO[row][c4];
    *(float4*)(outg + ((size_t)bh * S_ + q0 + row) * D_ + c4) = val;
  }
}

extern "C" void kernel_launch(void* const* d_in, const int* in_sizes, int n_in,
                              void* d_out, int out_size, void* d_ws, size_t ws_size,
                              hipStream_t stream) {
  const float* q    = (const float*)d_in[0];
  const float* k    = (const float*)d_in[1];
  const float* v    = (const float*)d_in[2];
  const int*   mask = (const int*)d_in[3];
  float* out = (float*)d_out;

  dim3 grid(S_ / BQ, B_ * H_);   // (32, 32) = 1024 blocks, 4 waves each
  attn_mfma<<<grid, 256, 0, stream>>>(q, k, v, mask, out);
}